// Round 1
// 269.465 us; speedup vs baseline: 1.0007x; 1.0007x over previous
//
#include <hip/hip_runtime.h>
#include <hip/hip_bf16.h>

#define G     32
#define NPG   512
#define EPG   8192
#define GN    16384        // G*NPG
#define ETOT  (G*EPG)      // 262144
#define CIN   64
#define H     128
#define NB    4
#define S     4096         // T*NPG
#define HEADS 4
#define HD    32
#define QKV   384

typedef __attribute__((ext_vector_type(8))) short short8;
typedef __attribute__((ext_vector_type(4))) float floatx4;

__device__ __forceinline__ float bf16_to_f32(unsigned short u) {
    unsigned int x = ((unsigned int)u) << 16;
    return __uint_as_float(x);
}
__device__ __forceinline__ unsigned short f32_to_bf16(float f) {
    __hip_bfloat16 h = (__hip_bfloat16)f;
    return *(unsigned short*)&h;
}
__device__ __forceinline__ float ldf(const void* p, long i, int f32) {
    return f32 ? ((const float*)p)[i] : bf16_to_f32(((const unsigned short*)p)[i]);
}

// ---------- runtime dtype detection ----------
__global__ void detect_kernel(const unsigned short* __restrict__ xraw,
                              const int* __restrict__ eiraw, int* __restrict__ flags) {
    __shared__ float smax[256];
    __shared__ int   sor[256];
    int t = threadIdx.x;
    float m = 0.f;
    for (int i = t; i < 4096; i += 256)
        m = fmaxf(m, fabsf(bf16_to_f32(xraw[i])));
    int orv = 0;
    for (int i = t; i < 2048; i += 256)
        orv |= eiraw[2 * i + 1];
    smax[t] = m; sor[t] = orv;
    __syncthreads();
    for (int off = 128; off > 0; off >>= 1) {
        if (t < off) {
            smax[t] = fmaxf(smax[t], smax[t + off]);
            sor[t] |= sor[t + off];
        }
        __syncthreads();
    }
    if (t == 0) {
        flags[0] = (smax[0] > 1000.f) ? 1 : 0;
        flags[1] = (sor[0] == 0) ? 1 : 0;
    }
}

// ---------- fused conversion: everything -> bf16 (weights pre-transposed) ----------
#define XN   (GN*CIN)          // x:      [0,      XN)
#define E1   (XN + H*CIN)      // W1T
#define E2   (E1 + H*H)        // W2T
#define E3   (E2 + QKV*H)      // Wqkv
#define E4   (E3 + H*H)        // Wo
#define E5   (E4 + H)          // b1
#define E6   (E5 + H)          // b2
#define E7   (E6 + QKV)        // bqkv
#define CTOT (E7 + H)          // bo
__global__ void conv_all_kernel(const void* x_raw, const void* W1_raw, const void* b1_raw,
                                const void* W2_raw, const void* b2_raw, const void* Wq_raw,
                                const void* bq_raw, const void* Wo_raw, const void* bo_raw,
                                unsigned short* __restrict__ xb,
                                unsigned short* __restrict__ W1T,
                                unsigned short* __restrict__ W2T,
                                unsigned short* __restrict__ Wqb,
                                unsigned short* __restrict__ Wob,
                                float* __restrict__ b1f, float* __restrict__ b2f,
                                float* __restrict__ bqf, float* __restrict__ bof,
                                const int* __restrict__ flags) {
    int i = blockIdx.x * blockDim.x + threadIdx.x;
    if (i >= CTOT) return;
    int f32 = flags[0];
    if (i < XN) {
        xb[i] = f32_to_bf16(ldf(x_raw, i, f32));
    } else if (i < E1) {       // W1T[c][r] = W1[r][c], [H out][CIN in]
        int j = i - XN, c = j / CIN, r = j - c * CIN;
        W1T[j] = f32_to_bf16(ldf(W1_raw, (long)r * H + c, f32));
    } else if (i < E2) {       // W2T[c][r] = W2[r][c]
        int j = i - E1, c = j >> 7, r = j & 127;
        W2T[j] = f32_to_bf16(ldf(W2_raw, (long)r * H + c, f32));
    } else if (i < E3) {       // in_proj_w already [out][in]
        int j = i - E2;
        Wqb[j] = f32_to_bf16(ldf(Wq_raw, j, f32));
    } else if (i < E4) {
        int j = i - E3;
        Wob[j] = f32_to_bf16(ldf(Wo_raw, j, f32));
    } else if (i < E5) { b1f[i - E4] = ldf(b1_raw, i - E4, f32); }
    else if (i < E6) { b2f[i - E5] = ldf(b2_raw, i - E5, f32); }
    else if (i < E7) { bqf[i - E6] = ldf(bq_raw, i - E6, f32); }
    else             { bof[i - E7] = ldf(bo_raw, i - E7, f32); }
}

// ---------- edges / CSR ----------
__global__ void edges_kernel(const int* __restrict__ ei, int* __restrict__ srcA,
                             int* __restrict__ dstA, const int* __restrict__ flags) {
    int t = blockIdx.x * blockDim.x + threadIdx.x;
    if (t >= ETOT) return;
    int g = t >> 13, e = t & (EPG - 1);
    int sh = flags[1];
    long long si = ((long long)(g * 2 + 0) * EPG + e) << sh;
    long long di = ((long long)(g * 2 + 1) * EPG + e) << sh;
    srcA[t] = g * NPG + ei[si];
    dstA[t] = g * NPG + ei[di];
}

__global__ void count_kernel(const int* __restrict__ dstA, int* __restrict__ cnt) {
    int t = blockIdx.x * blockDim.x + threadIdx.x;
    if (t >= ETOT) return;
    atomicAdd(&cnt[dstA[t]], 1);
}

__global__ void scan_kernel(const int* __restrict__ cnt, int* __restrict__ row_start,
                            int* __restrict__ fill_pos, float* __restrict__ dinv) {
    __shared__ int tmp[NPG];
    int g = blockIdx.x, t = threadIdx.x;
    int c = cnt[g * NPG + t];
    tmp[t] = c;
    __syncthreads();
    for (int off = 1; off < NPG; off <<= 1) {
        int v = (t >= off) ? tmp[t - off] : 0;
        __syncthreads();
        tmp[t] += v;
        __syncthreads();
    }
    int excl = tmp[t] - c;
    int rs = g * EPG + excl;
    row_start[g * NPG + t] = rs;
    fill_pos[g * NPG + t]  = rs;
    dinv[g * NPG + t] = 1.0f / sqrtf((float)c + 1.0f);
}

__global__ void fill_kernel(const int* __restrict__ srcA, const int* __restrict__ dstA,
                            int* __restrict__ fill_pos, int* __restrict__ csr_src) {
    int t = blockIdx.x * blockDim.x + threadIdx.x;
    if (t >= ETOT) return;
    int pos = atomicAdd(&fill_pos[dstA[t]], 1);
    csr_src[pos] = srcA[t];
}

// ---------- MFMA GEMM: Y[row][col] = (A[row][:] . B[col][:]) * dinv[row]  (bf16 out)
template<int KD>
__global__ __launch_bounds__(256) void mm_gcn_kernel(const unsigned short* __restrict__ A,
        const unsigned short* __restrict__ B, const float* __restrict__ dinv,
        unsigned short* __restrict__ Y) {
    int tid = threadIdx.x, wave = tid >> 6, lane = tid & 63, m = lane & 15, quad = lane >> 4;
    int row0 = blockIdx.x * 64 + wave * 16;
    floatx4 acc[8] = {};
    for (int kc = 0; kc < KD; kc += 32) {
        short8 af = *(const short8*)&A[(size_t)(row0 + m) * KD + kc + quad * 8];
#pragma unroll
        for (int t = 0; t < 8; t++) {
            short8 bf = *(const short8*)&B[(size_t)(t * 16 + m) * KD + kc + quad * 8];
            acc[t] = __builtin_amdgcn_mfma_f32_16x16x32_bf16(af, bf, acc[t], 0, 0, 0);
        }
    }
    int rbase = row0 + quad * 4;
    float4 dv4 = *(const float4*)&dinv[rbase];
    float dv[4] = {dv4.x, dv4.y, dv4.z, dv4.w};
#pragma unroll
    for (int t = 0; t < 8; t++) {
        int col = t * 16 + m;
#pragma unroll
        for (int r = 0; r < 4; r++)
            Y[(size_t)(rbase + r) * H + col] = f32_to_bf16(acc[t][r] * dv[r]);
    }
}

// ---------- GCN aggregation (bf16 in/out, f32 accum), gather unrolled x4 ----------
__global__ void agg_kernel(const unsigned short* __restrict__ y,
                           const int* __restrict__ row_start, const int* __restrict__ cnt,
                           const int* __restrict__ csr_src, const float* __restrict__ dinv,
                           const float* __restrict__ bias, unsigned short* __restrict__ hout) {
    int i = blockIdx.x;
    int c = threadIdx.x;
    float acc = bf16_to_f32(y[(size_t)i * H + c]);   // self-loop
    int rs = row_start[i], n = cnt[i];
    int p = 0;
    for (; p + 4 <= n; p += 4) {
        int s0 = csr_src[rs + p + 0];
        int s1 = csr_src[rs + p + 1];
        int s2 = csr_src[rs + p + 2];
        int s3 = csr_src[rs + p + 3];
        float a0 = bf16_to_f32(y[(size_t)s0 * H + c]);
        float a1 = bf16_to_f32(y[(size_t)s1 * H + c]);
        float a2 = bf16_to_f32(y[(size_t)s2 * H + c]);
        float a3 = bf16_to_f32(y[(size_t)s3 * H + c]);
        acc += (a0 + a1) + (a2 + a3);
    }
    for (; p < n; p++)
        acc += bf16_to_f32(y[(size_t)csr_src[rs + p] * H + c]);
    hout[(size_t)i * H + c] = f32_to_bf16(acc * dinv[i] + bias[c]);
}

// ---------- QKV GEMM (N=384) with blocked epilogue ----------
// Q pre-scale now folds log2(e) so attention can use raw v_exp_f32 (2^x).
__global__ __launch_bounds__(256) void mmqkv_kernel(const unsigned short* __restrict__ A,
        const unsigned short* __restrict__ B, const float* __restrict__ bias,
        unsigned short* __restrict__ Qx, unsigned short* __restrict__ Kx,
        unsigned short* __restrict__ Vtx) {
    int tid = threadIdx.x, wave = tid >> 6, lane = tid & 63, m = lane & 15, quad = lane >> 4;
    int row0 = blockIdx.x * 64 + wave * 16;
    floatx4 acc[24] = {};
    for (int kc = 0; kc < H; kc += 32) {
        short8 af = *(const short8*)&A[(size_t)(row0 + m) * H + kc + quad * 8];
#pragma unroll
        for (int t = 0; t < 24; t++) {
            short8 bf = *(const short8*)&B[(size_t)(t * 16 + m) * H + kc + quad * 8];
            acc[t] = __builtin_amdgcn_mfma_f32_16x16x32_bf16(af, bf, acc[t], 0, 0, 0);
        }
    }
    int rbase = row0 + quad * 4;                    // rows rbase..rbase+3, same batch
    int b = rbase >> 12, s0 = rbase & (S - 1);
#pragma unroll
    for (int t = 0; t < 24; t++) {
        int j = t * 16 + m;                         // 0..383
        float bj = bias[j];
        int jj = j & 127, head = jj >> 5, hd = jj & 31;
        int bh = b * HEADS + head;
        if (t < 8) {                                // Q (pre-scaled by log2e/sqrt(hd))
#pragma unroll
            for (int r = 0; r < 4; r++)
                Qx[((size_t)bh * S + s0 + r) * HD + hd] =
                    f32_to_bf16((acc[t][r] + bj) *
                                (0.17677669529663687f * 1.4426950408889634f));
        } else if (t < 16) {                        // K
#pragma unroll
            for (int r = 0; r < 4; r++)
                Kx[((size_t)bh * S + s0 + r) * HD + hd] = f32_to_bf16(acc[t][r] + bj);
        } else {                                    // V transposed
#pragma unroll
            for (int r = 0; r < 4; r++)
                Vtx[((size_t)bh * HD + hd) * S + s0 + r] = f32_to_bf16(acc[t][r] + bj);
        }
    }
}

// ---------- MFMA flash attention v4: zero-LDS, in-register P transpose ----------
// Swapped QK^T (mfma(K,Q)) puts a full P row per lane; cvt_pk_bf16 packs pairs and
// permlane32/16_swap redistribute them into the exact PV A-fragment layout
// (lane(m,quad) = P[q=m][k=8*quad..8*quad+7]).  Softmax denominator l is computed
// on the MFMA pipe (P x ones fragment) and lands row-aligned with the O accumulators,
// so the epilogue needs no cross-lane reduction at all.
// grid (S/128, HEADS, NB), block 256, LDS 0.
__global__ __launch_bounds__(256) void attn4_kernel(
        const unsigned short* __restrict__ Qx, const unsigned short* __restrict__ Kx,
        const unsigned short* __restrict__ Vtx, unsigned short* __restrict__ Ob) {
    int tid = threadIdx.x, wave = tid >> 6, lane = tid & 63;
    int m = lane & 15, quad = lane >> 4;
    int bh = blockIdx.z * HEADS + blockIdx.y;
    const unsigned short* Qb  = Qx  + (size_t)bh * S * HD;
    const unsigned short* Kb  = Kx  + (size_t)bh * S * HD;
    const unsigned short* Vtb = Vtx + (size_t)bh * HD * S;

    int q0 = blockIdx.x * 128 + wave * 32;
    short8 qa = *(const short8*)&Qb[(size_t)(q0 + m) * HD + quad * 8];
    short8 qb = *(const short8*)&Qb[(size_t)(q0 + 16 + m) * HD + quad * 8];

    floatx4 oa0 = {}, oa1 = {}, ob0 = {}, ob1 = {};
    floatx4 la = {}, lb = {};                       // row-sum accumulators (MFMA pipe)

    short8 ones = {16256, 16256, 16256, 16256, 16256, 16256, 16256, 16256}; // bf16 1.0

    // chunk 0 K/V
    short8 kf0 = *(const short8*)&Kb[(size_t)m * HD + quad * 8];
    short8 kf1 = *(const short8*)&Kb[(size_t)(m + 16) * HD + quad * 8];
    short8 vc0 = *(const short8*)&Vtb[(size_t)m * S + quad * 8];
    short8 vc1 = *(const short8*)&Vtb[(size_t)(m + 16) * S + quad * 8];

    for (int i = 0; i < S / 32; i++) {
        // swapped QK^T: lane(m,quad) gets P^T[k=quad*4+r][q=m] (+16 for second tile)
        floatx4 z = {};
        floatx4 ta0 = __builtin_amdgcn_mfma_f32_16x16x32_bf16(kf0, qa, z, 0, 0, 0);
        floatx4 ta1 = __builtin_amdgcn_mfma_f32_16x16x32_bf16(kf1, qa, z, 0, 0, 0);
        floatx4 tb0 = __builtin_amdgcn_mfma_f32_16x16x32_bf16(kf0, qb, z, 0, 0, 0);
        floatx4 tb1 = __builtin_amdgcn_mfma_f32_16x16x32_bf16(kf1, qb, z, 0, 0, 0);

        // rotate V, prefetch chunk i+1 (wrap: harmless valid loads)
        short8 vp0 = vc0, vp1 = vc1;
        int ktn = ((i + 1) * 32) & (S - 1);
        kf0 = *(const short8*)&Kb[(size_t)(ktn + m) * HD + quad * 8];
        kf1 = *(const short8*)&Kb[(size_t)(ktn + m + 16) * HD + quad * 8];
        vc0 = *(const short8*)&Vtb[(size_t)m * S + ktn + quad * 8];
        vc1 = *(const short8*)&Vtb[(size_t)(m + 16) * S + ktn + quad * 8];

        // exp2 (Q was pre-scaled by log2e/sqrt(hd)) -> raw v_exp_f32, no mul
        float pa0 = __builtin_amdgcn_exp2f(ta0[0]);
        float pa1 = __builtin_amdgcn_exp2f(ta0[1]);
        float pa2 = __builtin_amdgcn_exp2f(ta0[2]);
        float pa3 = __builtin_amdgcn_exp2f(ta0[3]);
        float pa4 = __builtin_amdgcn_exp2f(ta1[0]);
        float pa5 = __builtin_amdgcn_exp2f(ta1[1]);
        float pa6 = __builtin_amdgcn_exp2f(ta1[2]);
        float pa7 = __builtin_amdgcn_exp2f(ta1[3]);
        float pb0 = __builtin_amdgcn_exp2f(tb0[0]);
        float pb1 = __builtin_amdgcn_exp2f(tb0[1]);
        float pb2 = __builtin_amdgcn_exp2f(tb0[2]);
        float pb3 = __builtin_amdgcn_exp2f(tb0[3]);
        float pb4 = __builtin_amdgcn_exp2f(tb1[0]);
        float pb5 = __builtin_amdgcn_exp2f(tb1[1]);
        float pb6 = __builtin_amdgcn_exp2f(tb1[2]);
        float pb7 = __builtin_amdgcn_exp2f(tb1[3]);

        // pack pairs to bf16 (one op per 2 converts)
        unsigned int wa0, wa1, wa2, wa3, wb0, wb1, wb2, wb3;
        asm("v_cvt_pk_bf16_f32 %0, %1, %2" : "=v"(wa0) : "v"(pa0), "v"(pa1));
        asm("v_cvt_pk_bf16_f32 %0, %1, %2" : "=v"(wa1) : "v"(pa2), "v"(pa3));
        asm("v_cvt_pk_bf16_f32 %0, %1, %2" : "=v"(wa2) : "v"(pa4), "v"(pa5));
        asm("v_cvt_pk_bf16_f32 %0, %1, %2" : "=v"(wa3) : "v"(pa6), "v"(pa7));
        asm("v_cvt_pk_bf16_f32 %0, %1, %2" : "=v"(wb0) : "v"(pb0), "v"(pb1));
        asm("v_cvt_pk_bf16_f32 %0, %1, %2" : "=v"(wb1) : "v"(pb2), "v"(pb3));
        asm("v_cvt_pk_bf16_f32 %0, %1, %2" : "=v"(wb2) : "v"(pb4), "v"(pb5));
        asm("v_cvt_pk_bf16_f32 %0, %1, %2" : "=v"(wb3) : "v"(pb6), "v"(pb7));

        // in-register transpose: hi-half(dst) <-> lo-half(src), then row1<->row0 per pair
        asm("v_permlane32_swap_b32 %0, %1" : "+v"(wa0), "+v"(wa2));
        asm("v_permlane32_swap_b32 %0, %1" : "+v"(wa1), "+v"(wa3));
        asm("v_permlane16_swap_b32 %0, %1" : "+v"(wa0), "+v"(wa2));
        asm("v_permlane16_swap_b32 %0, %1" : "+v"(wa1), "+v"(wa3));
        asm("v_permlane32_swap_b32 %0, %1" : "+v"(wb0), "+v"(wb2));
        asm("v_permlane32_swap_b32 %0, %1" : "+v"(wb1), "+v"(wb3));
        asm("v_permlane16_swap_b32 %0, %1" : "+v"(wb0), "+v"(wb2));
        asm("v_permlane16_swap_b32 %0, %1" : "+v"(wb1), "+v"(wb3));

        union PW { unsigned int u[4]; short8 s8; };
        PW pwa, pwb;
        pwa.u[0] = wa0; pwa.u[1] = wa1; pwa.u[2] = wa2; pwa.u[3] = wa3;
        pwb.u[0] = wb0; pwb.u[1] = wb1; pwb.u[2] = wb2; pwb.u[3] = wb3;

        // PV + row-sum l, all on the MFMA pipe
        oa0 = __builtin_amdgcn_mfma_f32_16x16x32_bf16(pwa.s8, vp0, oa0, 0, 0, 0);
        oa1 = __builtin_amdgcn_mfma_f32_16x16x32_bf16(pwa.s8, vp1, oa1, 0, 0, 0);
        la  = __builtin_amdgcn_mfma_f32_16x16x32_bf16(pwa.s8, ones, la, 0, 0, 0);
        ob0 = __builtin_amdgcn_mfma_f32_16x16x32_bf16(pwb.s8, vp0, ob0, 0, 0, 0);
        ob1 = __builtin_amdgcn_mfma_f32_16x16x32_bf16(pwb.s8, vp1, ob1, 0, 0, 0);
        lb  = __builtin_amdgcn_mfma_f32_16x16x32_bf16(pwb.s8, ones, lb, 0, 0, 0);
    }

    // epilogue: l is already row-aligned with O (row = quad*4+r), no shuffles
    int grow = blockIdx.z * S + q0 + quad * 4;
    int col = blockIdx.y * HD + m;
#pragma unroll
    for (int r = 0; r < 4; r++) {
        float iar = 1.f / la[r], ibr = 1.f / lb[r];
        Ob[(size_t)(grow + r) * H + col]           = f32_to_bf16(oa0[r] * iar);
        Ob[(size_t)(grow + r) * H + col + 16]      = f32_to_bf16(oa1[r] * iar);
        Ob[(size_t)(grow + 16 + r) * H + col]      = f32_to_bf16(ob0[r] * ibr);
        Ob[(size_t)(grow + 16 + r) * H + col + 16] = f32_to_bf16(ob1[r] * ibr);
    }
}

// ---------- output projection GEMM (N=128) + bias, dual-dtype store ----------
__global__ __launch_bounds__(256) void mmout_kernel(const unsigned short* __restrict__ A,
        const unsigned short* __restrict__ B, const float* __restrict__ bias,
        void* __restrict__ out, const int* __restrict__ flags) {
    int tid = threadIdx.x, wave = tid >> 6, lane = tid & 63, m = lane & 15, quad = lane >> 4;
    int row0 = blockIdx.x * 64 + wave * 16;
    floatx4 acc[8] = {};
    for (int kc = 0; kc < H; kc += 32) {
        short8 af = *(const short8*)&A[(size_t)(row0 + m) * H + kc + quad * 8];
#pragma unroll
        for (int t = 0; t < 8; t++) {
            short8 bf = *(const short8*)&B[(size_t)(t * 16 + m) * H + kc + quad * 8];
            acc[t] = __builtin_amdgcn_mfma_f32_16x16x32_bf16(af, bf, acc[t], 0, 0, 0);
        }
    }
    int rbase = row0 + quad * 4;
    int f32o = flags[0];
#pragma unroll
    for (int t = 0; t < 8; t++) {
        int col = t * 16 + m;
        float bj = bias[col];
#pragma unroll
        for (int r = 0; r < 4; r++) {
            float v = acc[t][r] + bj;
            if (f32o) ((float*)out)[(size_t)(rbase + r) * H + col] = v;
            else ((unsigned short*)out)[(size_t)(rbase + r) * H + col] = f32_to_bf16(v);
        }
    }
}

extern "C" void kernel_launch(void* const* d_in, const int* in_sizes, int n_in,
                              void* d_out, int out_size, void* d_ws, size_t ws_size,
                              hipStream_t stream) {
    const void* x_raw    = d_in[0];
    const int*  ei_raw   = (const int*)d_in[1];
    const void* W1_raw   = d_in[2];
    const void* b1_raw   = d_in[3];
    const void* W2_raw   = d_in[4];
    const void* b2_raw   = d_in[5];
    const void* Wq_raw   = d_in[6];
    const void* bq_raw   = d_in[7];
    const void* Wo_raw   = d_in[8];
    const void* bo_raw   = d_in[9];

    char* ws = (char*)d_ws;
    size_t o = 0;
    auto alloc = [&](size_t bytes) { void* p = ws + o; o += (bytes + 1023) & ~1023ull; return p; };

    int*   flags     = (int*)  alloc(1024);
    int*   cnt       = (int*)  alloc((size_t)GN * 4);
    int*   row_start = (int*)  alloc((size_t)GN * 4);
    int*   fill_pos  = (int*)  alloc((size_t)GN * 4);
    float* dinv      = (float*)alloc((size_t)GN * 4);
    int*   srcA      = (int*)  alloc((size_t)ETOT * 4);
    int*   dstA      = (int*)  alloc((size_t)ETOT * 4);
    int*   csr_src   = (int*)  alloc((size_t)ETOT * 4);
    unsigned short* xb   = (unsigned short*)alloc((size_t)GN * CIN * 2);
    unsigned short* W1T  = (unsigned short*)alloc((size_t)H * CIN * 2);
    unsigned short* W2T  = (unsigned short*)alloc((size_t)H * H * 2);
    unsigned short* Wqb  = (unsigned short*)alloc((size_t)QKV * H * 2);
    unsigned short* Wob  = (unsigned short*)alloc((size_t)H * H * 2);
    float* b1f = (float*)alloc(H * 4);
    float* b2f = (float*)alloc(H * 4);
    float* bqf = (float*)alloc(QKV * 4);
    float* bof = (float*)alloc(H * 4);
    unsigned short* y_bf = (unsigned short*)alloc((size_t)GN * H * 2);
    unsigned short* h_bf = (unsigned short*)alloc((size_t)GN * H * 2);
    unsigned short* Qx   = (unsigned short*)alloc((size_t)16 * S * HD * 2);
    unsigned short* Kx   = (unsigned short*)alloc((size_t)16 * S * HD * 2);
    unsigned short* Vtx  = (unsigned short*)alloc((size_t)16 * S * HD * 2);
    unsigned short* Obf  = y_bf;   // y dead after second agg

    detect_kernel<<<1, 256, 0, stream>>>((const unsigned short*)x_raw, ei_raw, flags);

    conv_all_kernel<<<(CTOT + 255) / 256, 256, 0, stream>>>(
        x_raw, W1_raw, b1_raw, W2_raw, b2_raw, Wq_raw, bq_raw, Wo_raw, bo_raw,
        xb, W1T, W2T, Wqb, Wob, b1f, b2f, bqf, bof, flags);

    edges_kernel<<<ETOT / 256, 256, 0, stream>>>(ei_raw, srcA, dstA, flags);
    hipMemsetAsync(cnt, 0, (size_t)GN * 4, stream);
    count_kernel<<<ETOT / 256, 256, 0, stream>>>(dstA, cnt);
    scan_kernel<<<G, NPG, 0, stream>>>(cnt, row_start, fill_pos, dinv);
    fill_kernel<<<ETOT / 256, 256, 0, stream>>>(srcA, dstA, fill_pos, csr_src);

    // GCN layer 1
    mm_gcn_kernel<CIN><<<GN / 64, 256, 0, stream>>>(xb, W1T, dinv, y_bf);
    agg_kernel<<<GN, H, 0, stream>>>(y_bf, row_start, cnt, csr_src, dinv, b1f, h_bf);
    // GCN layer 2
    mm_gcn_kernel<H><<<GN / 64, 256, 0, stream>>>(h_bf, W2T, dinv, y_bf);
    agg_kernel<<<GN, H, 0, stream>>>(y_bf, row_start, cnt, csr_src, dinv, b2f, h_bf);

    // attention
    mmqkv_kernel<<<GN / 64, 256, 0, stream>>>(h_bf, Wqb, bqf, Qx, Kx, Vtx);
    attn4_kernel<<<dim3(S / 128, HEADS, NB), 256, 0, stream>>>(Qx, Kx, Vtx, Obf);
    mmout_kernel<<<GN / 64, 256, 0, stream>>>(Obf, Wob, bof, d_out, flags);
}